// Round 1
// baseline (286.651 us; speedup 1.0000x reference)
//
#include <hip/hip_runtime.h>
#include <hip/hip_bf16.h>

#define NUM_Q_MAX 50000      // max valid query id (inclusive)
#define DIM_KEY 128
#define DIM_VAL 256
#define WF_COLS 384          // DIM_VAL + DIM_KEY
#define DIM_HID 512
#define MEMN    50
#define KDIM    192          // folded feature length: [0,50) corr, [56,184) embed, rest 0
#define EOFF    56
#define PITCH   200          // LDS row pitch in bf16 elems (400B -> 16 mod 128 slot stride)
#define QB      64
#define HT      64

__device__ __forceinline__ float blo(unsigned u){ return __uint_as_float(u << 16); }
__device__ __forceinline__ float bhi(unsigned u){ return __uint_as_float(u & 0xffff0000u); }
__device__ __forceinline__ float b2f(unsigned short s){ return __uint_as_float(((unsigned)s) << 16); }
__device__ __forceinline__ unsigned short f2b(float x){
    unsigned u = __float_as_uint(x);
    u += 0x7fffu + ((u >> 16) & 1u);     // round-to-nearest-even
    return (unsigned short)(u >> 16);
}

// ---------------------------------------------------------------------------
// Kernel P: WC[h][j] = (j<50)   ? dot(W_f[h, 0:256], V[j, :])      (G = W_f[:, :256] @ V.T)
//                      (56<=j<184)? W_f[h, 256 + (j-56)]
//                      else 0
// ---------------------------------------------------------------------------
__global__ void prep_kernel(const float* __restrict__ Wf, const float* __restrict__ Vm,
                            unsigned short* __restrict__ WC){
    const int h = blockIdx.x;
    const int t = threadIdx.x;
    for (int j = t; j < KDIM; j += 64) {
        float val = 0.f;
        if (j < MEMN) {
            const float4* wr = (const float4*)(Wf + h * WF_COLS);
            const float4* vr = (const float4*)(Vm + j * DIM_VAL);
            float s = 0.f;
            for (int v = 0; v < DIM_VAL / 4; ++v) {
                float4 a = wr[v], b = vr[v];
                s += a.x*b.x + a.y*b.y + a.z*b.z + a.w*b.w;
            }
            val = s;
        } else if (j >= EOFF && j < EOFF + DIM_KEY) {
            val = Wf[h * WF_COLS + DIM_VAL + (j - EOFF)];
        }
        WC[h * KDIM + j] = f2b(val);
    }
}

// ---------------------------------------------------------------------------
// Kernel A: per query id u: p[u] = sigmoid( sum_h w_p[h]*relu( WC[h]·x(u) + b_f[h] ) + b_p )
//           where x(u) = [softmax(K·e(u)) ‖ e(u)] (bf16 in LDS), e(u)=embed_table[u]
// ---------------------------------------------------------------------------
__global__ void __launch_bounds__(256)
table_kernel(const float* __restrict__ Kmem, const float* __restrict__ emb,
             const unsigned short* __restrict__ WC,
             const float* __restrict__ bfv, const float* __restrict__ wpv,
             const float* __restrict__ bpv, float* __restrict__ table){
    __shared__ __align__(16) unsigned short xf[QB * PITCH];
    __shared__ __align__(16) unsigned short wfs[HT * PITCH];
    const int tid = threadIdx.x;
    const int u0  = blockIdx.x * QB;

    // ---- phase 1a: embed rows -> xf (bf16), zero the pad regions ----
    #pragma unroll
    for (int n = 0; n < 4; ++n) {
        int c  = tid + 256 * n;          // 1024 chunks = 64 rows * 16 chunks of 8
        int qi = c >> 4, c8 = c & 15;
        int u  = u0 + qi; if (u > NUM_Q_MAX) u = NUM_Q_MAX;
        const float4* src = (const float4*)(emb + (long)u * DIM_KEY + c8 * 8);
        float4 f0 = src[0], f1 = src[1];
        uint4 w;
        w.x = (unsigned)f2b(f0.x) | ((unsigned)f2b(f0.y) << 16);
        w.y = (unsigned)f2b(f0.z) | ((unsigned)f2b(f0.w) << 16);
        w.z = (unsigned)f2b(f1.x) | ((unsigned)f2b(f1.y) << 16);
        w.w = (unsigned)f2b(f1.z) | ((unsigned)f2b(f1.w) << 16);
        *(uint4*)&xf[qi * PITCH + EOFF + c8 * 8] = w;
    }
    if (tid < QB) {
        for (int j = MEMN; j < EOFF; ++j)              xf[tid * PITCH + j] = 0;
        for (int j = EOFF + DIM_KEY; j < PITCH; ++j)   xf[tid * PITCH + j] = 0;
    }
    __syncthreads();

    // ---- phase 1b: logits[qi][m] = dot(e(qi), Kmem[m]) -> xf[qi][m] (bf16) ----
    for (int n = 0; n < 13; ++n) {
        int T = tid + (n << 8);
        int qi = T & 63, m = T >> 6;
        if (m < MEMN) {
            const uint4*  er = (const uint4*)&xf[qi * PITCH + EOFF];
            const float4* kr = (const float4*)(Kmem + m * DIM_KEY);
            float s = 0.f;
            #pragma unroll
            for (int b = 0; b < 16; ++b) {
                uint4  e8 = er[b];
                float4 k0 = kr[2*b], k1 = kr[2*b + 1];
                s += blo(e8.x)*k0.x + bhi(e8.x)*k0.y + blo(e8.y)*k0.z + bhi(e8.y)*k0.w
                   + blo(e8.z)*k1.x + bhi(e8.z)*k1.y + blo(e8.w)*k1.z + bhi(e8.w)*k1.w;
            }
            xf[qi * PITCH + m] = f2b(s);
        }
    }
    __syncthreads();

    // ---- phase 1c: softmax over the 50 logits per query ----
    if (tid < QB) {
        unsigned short* row = &xf[tid * PITCH];
        float mx = -1e30f;
        for (int m = 0; m < MEMN; ++m) mx = fmaxf(mx, b2f(row[m]));
        float sum = 0.f;
        for (int m = 0; m < MEMN; ++m) {
            float ev = __expf(b2f(row[m]) - mx);
            sum += ev;
            row[m] = f2b(ev);
        }
        float inv = 1.f / sum;
        for (int m = 0; m < MEMN; ++m) row[m] = f2b(b2f(row[m]) * inv);
    }
    __syncthreads();

    // ---- phase 2: z[q][h] = WC[h]·x(q); psum[q] += w_p[h]*relu(z+b_f[h]) ----
    const int qg = tid & 15;     // q = qg + 16*i  (i=0..3)
    const int hg = tid >> 4;     // h = ht*HT + hg + 16*j  (j=0..3)
    float psum[4] = {0.f, 0.f, 0.f, 0.f};

    for (int ht = 0; ht < DIM_HID / HT; ++ht) {
        #pragma unroll
        for (int n = 0; n < 6; ++n) {
            int c = tid + 256 * n;        // 1536 chunks = 64 rows * 24 chunks of 8
            int r = c / 24, c8 = c % 24;
            *(uint4*)&wfs[r * PITCH + c8 * 8] =
                *(const uint4*)&WC[(ht * HT + r) * KDIM + c8 * 8];
        }
        __syncthreads();

        float acc[4][4];
        #pragma unroll
        for (int i = 0; i < 4; ++i)
            #pragma unroll
            for (int j = 0; j < 4; ++j) acc[i][j] = 0.f;

        for (int k = 0; k < KDIM; k += 8) {
            uint4 au[4], bu[4];
            #pragma unroll
            for (int i = 0; i < 4; ++i) au[i] = *(const uint4*)&xf[(qg + 16*i) * PITCH + k];
            #pragma unroll
            for (int j = 0; j < 4; ++j) bu[j] = *(const uint4*)&wfs[(hg + 16*j) * PITCH + k];
            #pragma unroll
            for (int w = 0; w < 4; ++w) {
                float al[4], ah[4], bl[4], bh4[4];
                #pragma unroll
                for (int i = 0; i < 4; ++i) {
                    unsigned uu = ((const unsigned*)&au[i])[w];
                    al[i] = blo(uu); ah[i] = bhi(uu);
                }
                #pragma unroll
                for (int j = 0; j < 4; ++j) {
                    unsigned uu = ((const unsigned*)&bu[j])[w];
                    bl[j] = blo(uu); bh4[j] = bhi(uu);
                }
                #pragma unroll
                for (int i = 0; i < 4; ++i)
                    #pragma unroll
                    for (int j = 0; j < 4; ++j)
                        acc[i][j] += al[i]*bl[j] + ah[i]*bh4[j];
            }
        }
        #pragma unroll
        for (int j = 0; j < 4; ++j) {
            int h = ht * HT + hg + 16 * j;
            float bb = bfv[h], ww = wpv[h];
            #pragma unroll
            for (int i = 0; i < 4; ++i) {
                float z = acc[i][j] + bb;
                if (z > 0.f) psum[i] += ww * z;
            }
        }
        __syncthreads();   // wfs re-staged next iter
    }

    // ---- reduce partial sums across the 16 hg-threads per query ----
    float* red = (float*)wfs;
    #pragma unroll
    for (int i = 0; i < 4; ++i) red[(qg + 16*i) * 16 + hg] = psum[i];
    __syncthreads();
    if (tid < QB) {
        float s = 0.f;
        #pragma unroll
        for (int g = 0; g < 16; ++g) s += red[tid * 16 + g];
        s += bpv[0];
        float p = 1.f / (1.f + __expf(-s));
        int u = u0 + tid;
        if (u <= NUM_Q_MAX) table[u] = p;
    }
}

// ---------------------------------------------------------------------------
// Kernel B: out[i] = table[q[i]]
// ---------------------------------------------------------------------------
__global__ void gather_kernel(const int* __restrict__ q, const float* __restrict__ table,
                              float* __restrict__ out, int n){
    int i = blockIdx.x * 256 + threadIdx.x;
    if (i < n) out[i] = table[q[i]];
}

extern "C" void kernel_launch(void* const* d_in, const int* in_sizes, int n_in,
                              void* d_out, int out_size, void* d_ws, size_t ws_size,
                              hipStream_t stream) {
    const int*   q    = (const int*)  d_in[0];
    // d_in[1] = a  (unused by the forward math)
    const float* Kmem = (const float*)d_in[2];
    const float* Vmem = (const float*)d_in[3];
    const float* emb  = (const float*)d_in[4];
    // d_in[5..8] = W_erase/b_erase/W_add/b_add (unused)
    const float* Wf   = (const float*)d_in[9];
    const float* bf   = (const float*)d_in[10];
    const float* wp   = (const float*)d_in[11];
    const float* bp   = (const float*)d_in[12];
    float* out = (float*)d_out;

    unsigned short* WC    = (unsigned short*)d_ws;                       // 512*192*2 B
    float*          table = (float*)((char*)d_ws + DIM_HID * KDIM * 2);  // 50048*4 B

    prep_kernel<<<DIM_HID, 64, 0, stream>>>(Wf, Vmem, WC);

    int nblk = (NUM_Q_MAX + 1 + QB - 1) / QB;   // 782
    table_kernel<<<nblk, 256, 0, stream>>>(Kmem, emb, WC, bf, wp, bp, table);

    gather_kernel<<<(out_size + 255) / 256, 256, 0, stream>>>(q, table, out, out_size);
}

// Round 2
// 53.759 us; speedup vs baseline: 5.3322x; 5.3322x over previous
//
#include <hip/hip_runtime.h>
#include <hip/hip_bf16.h>

#define NUM_Q_MAX 50000      // max valid query id (inclusive)
#define DIM_KEY 128
#define DIM_VAL 256
#define WF_COLS 384          // DIM_VAL + DIM_KEY
#define DIM_HID 512
#define MEMN    50
#define KDIM    192          // folded feature length: [0,50) corr, [56,184) embed, rest 0
#define EOFF    56
#define PITCH   200          // LDS row pitch in bf16 elems (400B rows -> 2-way bank alias, free)
#define QB      64

typedef __bf16 bf16x8 __attribute__((ext_vector_type(8)));
typedef float  f32x4  __attribute__((ext_vector_type(4)));
union Frag { uint4 u; bf16x8 b; };

__device__ __forceinline__ float blo(unsigned u){ return __uint_as_float(u << 16); }
__device__ __forceinline__ float bhi(unsigned u){ return __uint_as_float(u & 0xffff0000u); }
__device__ __forceinline__ float b2f(unsigned short s){ return __uint_as_float(((unsigned)s) << 16); }
__device__ __forceinline__ unsigned short f2b(float x){
    unsigned u = __float_as_uint(x);
    u += 0x7fffu + ((u >> 16) & 1u);     // round-to-nearest-even
    return (unsigned short)(u >> 16);
}

// ---------------------------------------------------------------------------
// Kernel P: WC[h][j] = (j<50)     ? dot(W_f[h, 0:256], V[j, :])   (G = W_f[:,:256] @ V.T)
//                      (56<=j<184)? W_f[h, 256 + (j-56)]
//                      else 0                                      (bf16, row-major 512x192)
// ---------------------------------------------------------------------------
__global__ void prep_kernel(const float* __restrict__ Wf, const float* __restrict__ Vm,
                            unsigned short* __restrict__ WC){
    const int h = blockIdx.x;
    const int t = threadIdx.x;
    for (int j = t; j < KDIM; j += 64) {
        float val = 0.f;
        if (j < MEMN) {
            const float4* wr = (const float4*)(Wf + h * WF_COLS);
            const float4* vr = (const float4*)(Vm + j * DIM_VAL);
            float s = 0.f;
            for (int v = 0; v < DIM_VAL / 4; ++v) {
                float4 a = wr[v], b = vr[v];
                s += a.x*b.x + a.y*b.y + a.z*b.z + a.w*b.w;
            }
            val = s;
        } else if (j >= EOFF && j < EOFF + DIM_KEY) {
            val = Wf[h * WF_COLS + DIM_VAL + (j - EOFF)];
        }
        WC[h * KDIM + j] = f2b(val);
    }
}

// Kernel K: Kb[64][128] bf16 <- Kmem[50][128] f32, rows 50..63 zero
__global__ void kb_kernel(const float* __restrict__ Kmem, unsigned short* __restrict__ Kb){
    int idx = blockIdx.x * 256 + threadIdx.x;   // 8192 total
    if (idx < 64 * DIM_KEY) {
        int row = idx >> 7;
        float v = (row < MEMN) ? Kmem[idx] : 0.f;
        Kb[idx] = f2b(v);
    }
}

// ---------------------------------------------------------------------------
// Kernel A: per query id u: p[u] = sigmoid( sum_h w_p[h]*relu( WC[h]·x(u) + b_f[h] ) + b_p )
//           x(u) = [softmax(K·e(u)) ‖ e(u)] (bf16 in LDS), e(u)=embed_table[u]
//           MFMA for both the logits (64x50x128) and the main GEMM (64x512x192).
// ---------------------------------------------------------------------------
__global__ void __launch_bounds__(256)
table_kernel(const float* __restrict__ emb,
             const unsigned short* __restrict__ WC,
             const unsigned short* __restrict__ Kb,
             const float* __restrict__ bfv, const float* __restrict__ wpv,
             const float* __restrict__ bpv, float* __restrict__ table){
    __shared__ __align__(16) unsigned short xf[QB * PITCH];
    __shared__ float red[QB][4];
    const int tid  = threadIdx.x;
    const int u0   = blockIdx.x * QB;
    const int lane = tid & 63;
    const int wv   = tid >> 6;          // wave id 0..3
    const int l15  = lane & 15;
    const int l4   = lane >> 4;

    // ---- phase 1a: embed rows -> xf (bf16), zero the pad regions ----
    #pragma unroll
    for (int n = 0; n < 4; ++n) {
        int c  = tid + 256 * n;          // 1024 chunks = 64 rows * 16 chunks of 8
        int qi = c >> 4, c8 = c & 15;
        int u  = u0 + qi; if (u > NUM_Q_MAX) u = NUM_Q_MAX;
        const float4* src = (const float4*)(emb + (long)u * DIM_KEY + c8 * 8);
        float4 f0 = src[0], f1 = src[1];
        uint4 w;
        w.x = (unsigned)f2b(f0.x) | ((unsigned)f2b(f0.y) << 16);
        w.y = (unsigned)f2b(f0.z) | ((unsigned)f2b(f0.w) << 16);
        w.z = (unsigned)f2b(f1.x) | ((unsigned)f2b(f1.y) << 16);
        w.w = (unsigned)f2b(f1.z) | ((unsigned)f2b(f1.w) << 16);
        *(uint4*)&xf[qi * PITCH + EOFF + c8 * 8] = w;
    }
    if (tid < QB) {
        for (int j = MEMN; j < EOFF; ++j)              xf[tid * PITCH + j] = 0;
        for (int j = EOFF + DIM_KEY; j < PITCH; ++j)   xf[tid * PITCH + j] = 0;
    }
    __syncthreads();

    // ---- phase 1b: logits via MFMA. wave wv does q-tile wv. S = e @ Kb^T ----
    {
        Frag ef[4];
        #pragma unroll
        for (int ks = 0; ks < 4; ++ks)
            ef[ks].u = *(const uint4*)&xf[(wv*16 + l15) * PITCH + EOFF + ks*32 + l4*8];
        #pragma unroll
        for (int nt = 0; nt < 4; ++nt) {
            f32x4 acc = {0.f, 0.f, 0.f, 0.f};
            #pragma unroll
            for (int ks = 0; ks < 4; ++ks) {
                Frag bK;
                bK.u = *(const uint4*)&Kb[(nt*16 + l15) * DIM_KEY + ks*32 + l4*8];
                acc = __builtin_amdgcn_mfma_f32_16x16x32_bf16(ef[ks].b, bK.b, acc, 0, 0, 0);
            }
            int mcol = nt*16 + l15;
            if (mcol < MEMN) {
                #pragma unroll
                for (int r = 0; r < 4; ++r)
                    xf[(wv*16 + l4*4 + r) * PITCH + mcol] = f2b(acc[r]);
            }
        }
    }
    __syncthreads();

    // ---- phase 1c: softmax over the 50 logits per query ----
    if (tid < QB) {
        unsigned short* row = &xf[tid * PITCH];
        float mx = -1e30f;
        for (int m = 0; m < MEMN; ++m) mx = fmaxf(mx, b2f(row[m]));
        float sum = 0.f;
        for (int m = 0; m < MEMN; ++m) {
            float ev = __expf(b2f(row[m]) - mx);
            sum += ev;
            row[m] = f2b(ev);
        }
        float inv = 1.f / sum;
        for (int m = 0; m < MEMN; ++m) row[m] = f2b(b2f(row[m]) * inv);
    }
    __syncthreads();

    // ---- phase 2: Z = x @ WC^T via MFMA; fused relu + w_p reduction ----
    // wave wv owns h-range [wv*128, wv*128+128) = 8 n-tiles; all 4 m-tiles.
    Frag af[4][6];
    #pragma unroll
    for (int m = 0; m < 4; ++m)
        #pragma unroll
        for (int ks = 0; ks < 6; ++ks)
            af[m][ks].u = *(const uint4*)&xf[(m*16 + l15) * PITCH + ks*32 + l4*8];

    float psum[4][4];
    #pragma unroll
    for (int m = 0; m < 4; ++m)
        #pragma unroll
        for (int r = 0; r < 4; ++r) psum[m][r] = 0.f;

    const int hbase = wv * 128;
    #pragma unroll
    for (int nt = 0; nt < 8; ++nt) {
        const int h0 = hbase + nt * 16;
        Frag bw[6];
        #pragma unroll
        for (int ks = 0; ks < 6; ++ks)
            bw[ks].u = *(const uint4*)&WC[(h0 + l15) * KDIM + ks*32 + l4*8];
        f32x4 acc[4];
        #pragma unroll
        for (int m = 0; m < 4; ++m) acc[m] = (f32x4){0.f, 0.f, 0.f, 0.f};
        #pragma unroll
        for (int ks = 0; ks < 6; ++ks)
            #pragma unroll
            for (int m = 0; m < 4; ++m)
                acc[m] = __builtin_amdgcn_mfma_f32_16x16x32_bf16(af[m][ks].b, bw[ks].b, acc[m], 0, 0, 0);
        const int h = h0 + l15;
        const float bb = bfv[h], ww = wpv[h];
        #pragma unroll
        for (int m = 0; m < 4; ++m)
            #pragma unroll
            for (int r = 0; r < 4; ++r) {
                float z = acc[m][r] + bb;
                if (z > 0.f) psum[m][r] += ww * z;
            }
    }

    // reduce across the 16 h-lanes (same l4 group) of this wave
    #pragma unroll
    for (int off = 1; off < 16; off <<= 1)
        #pragma unroll
        for (int m = 0; m < 4; ++m)
            #pragma unroll
            for (int r = 0; r < 4; ++r)
                psum[m][r] += __shfl_xor(psum[m][r], off, 64);

    if (l15 == 0) {
        #pragma unroll
        for (int m = 0; m < 4; ++m)
            #pragma unroll
            for (int r = 0; r < 4; ++r)
                red[m*16 + l4*4 + r][wv] = psum[m][r];
    }
    __syncthreads();

    if (tid < QB) {
        float s = red[tid][0] + red[tid][1] + red[tid][2] + red[tid][3] + bpv[0];
        float p = 1.f / (1.f + __expf(-s));
        int u = u0 + tid;
        if (u <= NUM_Q_MAX) table[u] = p;
    }
}

// ---------------------------------------------------------------------------
// Kernel B: out[i] = table[q[i]]
// ---------------------------------------------------------------------------
__global__ void gather_kernel(const int* __restrict__ q, const float* __restrict__ table,
                              float* __restrict__ out, int n){
    int i = blockIdx.x * 256 + threadIdx.x;
    if (i < n) out[i] = table[q[i]];
}

extern "C" void kernel_launch(void* const* d_in, const int* in_sizes, int n_in,
                              void* d_out, int out_size, void* d_ws, size_t ws_size,
                              hipStream_t stream) {
    const int*   q    = (const int*)  d_in[0];
    // d_in[1] = a (unused by forward math)
    const float* Kmem = (const float*)d_in[2];
    const float* Vmem = (const float*)d_in[3];
    const float* emb  = (const float*)d_in[4];
    // d_in[5..8] = W_erase/b_erase/W_add/b_add (unused)
    const float* Wf   = (const float*)d_in[9];
    const float* bf   = (const float*)d_in[10];
    const float* wp   = (const float*)d_in[11];
    const float* bp   = (const float*)d_in[12];
    float* out = (float*)d_out;

    unsigned short* WC    = (unsigned short*)d_ws;                         // 512*192*2 = 196608 B
    unsigned short* Kb    = (unsigned short*)((char*)d_ws + 196608);       // 64*128*2  =  16384 B
    float*          table = (float*)((char*)d_ws + 196608 + 16384);        // 50001*4 B

    prep_kernel<<<DIM_HID, 64, 0, stream>>>(Wf, Vmem, WC);
    kb_kernel<<<32, 256, 0, stream>>>(Kmem, Kb);

    int nblk = (NUM_Q_MAX + 1 + QB - 1) / QB;   // 782
    table_kernel<<<nblk, 256, 0, stream>>>(emb, WC, Kb, bf, wp, bp, table);

    gather_kernel<<<(out_size + 255) / 256, 256, 0, stream>>>(q, table, out, out_size);
}